// Round 5
// baseline (275.353 us; speedup 1.0000x reference)
//
#include <hip/hip_runtime.h>

typedef __attribute__((ext_vector_type(8))) short bf16x8;
typedef __attribute__((ext_vector_type(4))) float f32x4;
typedef __attribute__((ext_vector_type(4))) unsigned short u16x4;
typedef __attribute__((ext_vector_type(8))) unsigned short u16x8;
typedef unsigned short u16;
typedef unsigned int u32;

#define MFMA16(a,b,c) __builtin_amdgcn_mfma_f32_16x16x32_bf16(a,b,c,0,0,0)

// ---------- f32 -> (bf16 hi, bf16 lo) split ----------
// hi = truncate-to-bf16; lo = bf16(x - hi). 3-product MFMA ~ fp32-class accuracy.
__device__ __forceinline__ void split_f32(float x, u16 &hi, u16 &lo){
  unsigned u = __float_as_uint(x);
  unsigned hif = u & 0xFFFF0000u;
  float rest = x - __uint_as_float(hif);
  hi = (u16)(u >> 16);
  lo = (u16)(__float_as_uint(rest) >> 16);
}

// ---------- register fragments ----------
// M plane layout: [row][chunk c=0..15][8 u16 hi | 8 u16 lo], row stride 256 u16.
// Weight layout identical (row stride 256), rows = d' (output), cols = contraction.
struct MFrag { bf16x8 h[4], l[4]; };   // B-operand rows s=n*16+li, chunk k*4+lg  (32 VGPR)
struct WHf   { bf16x8 a[2], b[2]; };   // hi frags, two matrices, mm=0,1          (16 VGPR)
struct WLf   { bf16x8 a[2], b[2]; };   // lo frags                                 (16 VGPR)

__device__ __forceinline__ void load_M(const u16* __restrict__ mp, const u32 off[4], int k, MFrag &F){
  #pragma unroll
  for (int n=0;n<4;n++){
    F.h[n] = *(const bf16x8*)(mp + off[n] + k*64);
    F.l[n] = *(const bf16x8*)(mp + off[n] + k*64 + 8);
  }
}
__device__ __forceinline__ void load_wh(const u16* __restrict__ wa, const u16* __restrict__ wb,
                                        int rowbase, int k, WHf &F){
  #pragma unroll
  for (int mm=0;mm<2;mm++){
    F.a[mm] = *(const bf16x8*)(wa + rowbase + mm*4096 + k*64);
    F.b[mm] = *(const bf16x8*)(wb + rowbase + mm*4096 + k*64);
  }
}
__device__ __forceinline__ void load_wl(const u16* __restrict__ wa, const u16* __restrict__ wb,
                                        int rowbase, int k, WLf &F){
  #pragma unroll
  for (int mm=0;mm<2;mm++){
    F.a[mm] = *(const bf16x8*)(wa + rowbase + mm*4096 + k*64 + 8);
    F.b[mm] = *(const bf16x8*)(wb + rowbase + mm*4096 + k*64 + 8);
  }
}

// pre[s][d'] = relu(c[d'] - T[d'][s]) -> LDS plane set (b64 along d', slot-XOR swizzle)
__device__ __forceinline__ void write_pre(u16* ldsHi, u16* ldsLo,
    const f32x4 acc[2][4], const float4 cv[2], int wid, int lg, int li)
{
  #pragma unroll
  for (int mm=0;mm<2;mm++){
    const int g = wid*8 + mm*4 + lg;
    #pragma unroll
    for (int n=0;n<4;n++){
      const int row = n*16 + li;
      u16x4 h4, l4;
      #pragma unroll
      for (int r=0;r<4;r++){
        float cr = (r==0)?cv[mm].x:(r==1)?cv[mm].y:(r==2)?cv[mm].z:cv[mm].w;
        float p = fmaxf(cr - acc[mm][n][r], 0.f);
        u16 hh, ll; split_f32(p, hh, ll);
        h4[r] = hh; l4[r] = ll;
      }
      const int a = row*128 + (((g>>1) ^ li)<<3) + ((g&1)<<2);
      *(u16x4*)&ldsHi[a] = h4;
      *(u16x4*)&ldsLo[a] = l4;
    }
  }
}

// ---------- prep: c vectors, folded Wc = hw@wv, bc = hw@bv+hb, W2 split+interleave ----------
__global__ __launch_bounds__(128) void prep_kernel(
    const float* __restrict__ v1, const float* __restrict__ v2,
    const float* __restrict__ mt_w1, const float* __restrict__ mt_b1,
    const float* __restrict__ mt_w2, const float* __restrict__ mt_b2,
    const float* __restrict__ mt_wv, const float* __restrict__ mt_bv,
    const float* __restrict__ mts_w1, const float* __restrict__ mts_b1,
    const float* __restrict__ mts_w2, const float* __restrict__ mts_b2,
    const float* __restrict__ mts_wv, const float* __restrict__ mts_bv,
    const float* __restrict__ ht_w, const float* __restrict__ ht_b,
    const float* __restrict__ hts_w, const float* __restrict__ hts_b,
    u16* __restrict__ w2a, u16* __restrict__ w2b,
    u16* __restrict__ wc1, u16* __restrict__ wc2,
    float* __restrict__ c1, float* __restrict__ c2,
    float* __restrict__ bc1, float* __restrict__ bc2)
{
  const int blk = blockIdx.x;
  const int t = threadIdx.x;   // 128 threads
  if (blk < 128) {
    const bool second = blk >= 64;
    const int b = blk & 63;
    const float* x  = second ? v1 : v2;
    const float* w1 = second ? mts_w1 : mt_w1;
    const float* b1 = second ? mts_b1 : mt_b1;
    const float* b2 = second ? mts_b2 : mt_b2;
    float* c = second ? c2 : c1;
    __shared__ float xr[128];
    xr[t] = x[b*128 + t];
    __syncthreads();
    float s = 0.f;
    #pragma unroll 8
    for (int k=0;k<128;k++) s += w1[t*128 + k] * xr[k];
    c[b*128 + t] = s + b1[t] - b2[t];
  } else if (blk < 384) {
    const bool second = blk >= 256;
    const int e = blk - (second ? 256 : 128);
    const float* hw = second ? hts_w : ht_w;
    const float* wv = second ? mts_wv : mt_wv;
    const float* bv = second ? mts_bv : mt_bv;
    const float* hb = second ? hts_b : ht_b;
    u16* wc = second ? wc2 : wc1;
    float* bcp = second ? bc2 : bc1;
    float s = 0.f;
    #pragma unroll 8
    for (int k=0;k<128;k++) s += hw[e*128 + k] * wv[k*128 + t];
    u16 hi, lo; split_f32(s, hi, lo);
    int oi = e*256 + ((t>>3)<<4) + (t&7);
    wc[oi] = hi; wc[oi+8] = lo;
    __shared__ float red[128];
    red[t] = hw[e*128 + t] * bv[t];
    __syncthreads();
    for (int off=64; off>0; off>>=1){ if (t<off) red[t] += red[t+off]; __syncthreads(); }
    if (t==0) bcp[e] = red[0] + hb[e];
  } else {
    const int i = (blk-384)*128 + t;
    const int r = i >> 7, col = i & 127;
    const int oi = r*256 + ((col>>3)<<4) + (col&7);
    u16 hi, lo;
    split_f32(mt_w2[i], hi, lo);  w2a[oi] = hi; w2a[oi+8] = lo;
    split_f32(mts_w2[i], hi, lo); w2b[oi] = hi; w2b[oi+8] = lo;
  }
}

// ---------- main: 512 blocks (8 sb x 64 b), 8 s-tiles each, register-gathered M ----------
__global__ __launch_bounds__(256, 2) void main_kernel(
    const u16* __restrict__ mp,           // interleaved hi|lo plane [100000][16][8|8]
    const int* __restrict__ idx,
    const u16* __restrict__ w2a, const u16* __restrict__ w2b,
    const u16* __restrict__ wc1, const u16* __restrict__ wc2,
    const float* __restrict__ c1, const float* __restrict__ c2,
    const float* __restrict__ bc1, const float* __restrict__ bc2,
    float* __restrict__ wss)
{
  __shared__ u16 AHi[64*128];        // pre1 planes (16KB each)
  __shared__ u16 ALo[64*128];
  __shared__ u16 BHi[64*128];        // pre2 planes
  __shared__ u16 BLo[64*128];
  __shared__ float part[4][64][3];   // 3KB

  const int tid = threadIdx.x;
  const int wid = tid >> 6;
  const int lane = tid & 63;
  const int lg = lane >> 4, li = lane & 15;
  const int sb = blockIdx.x;         // 0..7
  const int b = blockIdx.y;          // 0..63
  const int ib = b*4096 + sb*512;
  const int rowbase = (wid*32 + li)*256 + lg*16;

  // block-constant vectors (parked)
  float4 cv1[2], cv2[2], b1v[2], b2v[2];
  #pragma unroll
  for (int mm=0;mm<2;mm++){
    cv1[mm] = *(const float4*)(c1 + b*128 + wid*32 + mm*16 + lg*4);
    cv2[mm] = *(const float4*)(c2 + b*128 + wid*32 + mm*16 + lg*4);
    b1v[mm] = *(const float4*)(bc1 + wid*32 + mm*16 + lg*4);
    b2v[mm] = *(const float4*)(bc2 + wid*32 + mm*16 + lg*4);
  }

  // prologue: idx + M k0 for tile 0
  u32 off[4];
  #pragma unroll
  for (int n=0;n<4;n++) off[n] = (u32)idx[ib + n*16 + li]*256 + lg*16;
  MFrag Mb[2];
  load_M(mp, off, 0, Mb[0]);

  for (int t=0; t<8; ++t){
    // ---- GEMM1: acc = W2 x M (M register-gathered, k-prefetched) ----
    f32x4 acc1[2][4], acc2[2][4];
    #pragma unroll
    for (int mm=0;mm<2;mm++)
      #pragma unroll
      for (int n=0;n<4;n++){ acc1[mm][n]=(f32x4)(0.f); acc2[mm][n]=(f32x4)(0.f); }
    {
      WHf wh[2]; WLf wl;
      load_wh(w2a, w2b, rowbase, 0, wh[0]);
      #pragma unroll
      for (int k=0;k<4;k++){
        if (k<3){ load_M(mp, off, k+1, Mb[(k+1)&1]); load_wh(w2a, w2b, rowbase, k+1, wh[(k+1)&1]); }
        load_wl(w2a, w2b, rowbase, k, wl);
        const MFrag &Mc = Mb[k&1];
        __builtin_amdgcn_s_setprio(1);
        #pragma unroll
        for (int n=0;n<4;n++){
          bf16x8 bh = Mc.h[n], bl = Mc.l[n];
          #pragma unroll
          for (int mm=0;mm<2;mm++){
            acc1[mm][n] = MFMA16(wh[k&1].a[mm], bh, acc1[mm][n]);
            acc2[mm][n] = MFMA16(wh[k&1].b[mm], bh, acc2[mm][n]);
            acc1[mm][n] = MFMA16(wh[k&1].a[mm], bl, acc1[mm][n]);
            acc2[mm][n] = MFMA16(wh[k&1].b[mm], bl, acc2[mm][n]);
            acc1[mm][n] = MFMA16(wl.a[mm], bh, acc1[mm][n]);
            acc2[mm][n] = MFMA16(wl.b[mm], bh, acc2[mm][n]);
          }
        }
        __builtin_amdgcn_s_setprio(0);
      }
    }

    // issue idx for next tile (covered by pre-writes + GEMM23)
    int nidx[4];
    if (t<7){
      #pragma unroll
      for (int n=0;n<4;n++) nidx[n] = idx[ib + (t+1)*64 + n*16 + li];
    }

    __syncthreads();   // prev GEMM23 plane reads + part reads done
    write_pre(AHi, ALo, acc1, cv1, wid, lg, li);
    write_pre(BHi, BLo, acc2, cv2, wid, lg, li);
    __syncthreads();   // pre planes visible

    // ---- fused GEMM2+GEMM3: h1 = Wc1 x pre1 (setA), h2 = Wc2 x pre2 (setB) ----
    f32x4 h1[2][4], h2[2][4];
    #pragma unroll
    for (int mm=0;mm<2;mm++)
      #pragma unroll
      for (int n=0;n<4;n++){ h1[mm][n]=(f32x4)(0.f); h2[mm][n]=(f32x4)(0.f); }
    {
      WHf vh[2]; WLf vl;
      load_wh(wc1, wc2, rowbase, 0, vh[0]);
      #pragma unroll
      for (int k=0;k<4;k++){
        if (k<3) load_wh(wc1, wc2, rowbase, k+1, vh[(k+1)&1]);
        load_wl(wc1, wc2, rowbase, k, vl);
        __builtin_amdgcn_s_setprio(1);
        #pragma unroll
        for (int n=0;n<4;n++){
          const int row = n*16 + li;
          const int a = row*128 + (((k*4+lg) ^ li)<<3);
          bf16x8 p1h = *(const bf16x8*)(AHi + a);
          bf16x8 p1l = *(const bf16x8*)(ALo + a);
          bf16x8 p2h = *(const bf16x8*)(BHi + a);
          bf16x8 p2l = *(const bf16x8*)(BLo + a);
          #pragma unroll
          for (int mm=0;mm<2;mm++){
            h1[mm][n] = MFMA16(vh[k&1].a[mm], p1h, h1[mm][n]);
            h2[mm][n] = MFMA16(vh[k&1].b[mm], p2h, h2[mm][n]);
            h1[mm][n] = MFMA16(vh[k&1].a[mm], p1l, h1[mm][n]);
            h2[mm][n] = MFMA16(vh[k&1].b[mm], p2l, h2[mm][n]);
            h1[mm][n] = MFMA16(vl.a[mm], p1h, h1[mm][n]);
            h2[mm][n] = MFMA16(vl.b[mm], p2h, h2[mm][n]);
          }
        }
        __builtin_amdgcn_s_setprio(0);
      }
    }

    // next tile's M k0 (flies during reduction + next GEMM1 start)
    if (t<7){
      #pragma unroll
      for (int n=0;n<4;n++) off[n] = (u32)nidx[n]*256 + lg*16;
      load_M(mp, off, 0, Mb[0]);
    }

    // ---- score partials ----
    #pragma unroll
    for (int n=0;n<4;n++){
      float p11=0.f, p22=0.f, p12=0.f;
      #pragma unroll
      for (int mm=0;mm<2;mm++){
        #pragma unroll
        for (int r=0;r<4;r++){
          float bb1 = (r==0)?b1v[mm].x:(r==1)?b1v[mm].y:(r==2)?b1v[mm].z:b1v[mm].w;
          float bb2 = (r==0)?b2v[mm].x:(r==1)?b2v[mm].y:(r==2)?b2v[mm].z:b2v[mm].w;
          float v1h = h1[mm][n][r] + bb1;
          float v2h = h2[mm][n][r] + bb2;
          p11 += v1h*v1h; p22 += v2h*v2h; p12 += v1h*v2h;
        }
      }
      p11 += __shfl_xor(p11, 16, 64); p11 += __shfl_xor(p11, 32, 64);
      p22 += __shfl_xor(p22, 16, 64); p22 += __shfl_xor(p22, 32, 64);
      p12 += __shfl_xor(p12, 16, 64); p12 += __shfl_xor(p12, 32, 64);
      if (lane < 16){
        part[wid][n*16+li][0] = p11;
        part[wid][n*16+li][1] = p22;
        part[wid][n*16+li][2] = p12;
      }
    }
    __syncthreads();   // partials visible
    if (tid < 64){
      float S11 = part[0][tid][0] + part[1][tid][0] + part[2][tid][0] + part[3][tid][0];
      float S22 = part[0][tid][1] + part[1][tid][1] + part[2][tid][1] + part[3][tid][1];
      float S12 = part[0][tid][2] + part[1][tid][2] + part[2][tid][2] + part[3][tid][2];
      float dot = S12 / sqrtf(S11 * S22);
      wss[(size_t)b*4096 + sb*512 + t*64 + tid] = expf((dot - 1.0f) * (1.0f/0.07f));
    }
  }
}

// ---------- split (+ optional copy): bank -> interleaved hi|lo plane ----------
__global__ __launch_bounds__(256) void split_copy_kernel(const float4* __restrict__ src,
    float4* __restrict__ dst, u16* __restrict__ mp, int n8, int docopy)
{
  int i = blockIdx.x*256 + threadIdx.x;
  const int stride = gridDim.x*256;
  for (; i < n8; i += stride){
    float4 f0 = src[2*i], f1 = src[2*i+1];
    if (docopy){ dst[2*i] = f0; dst[2*i+1] = f1; }
    u16x8 h, l; u16 hh, ll;
    split_f32(f0.x, hh, ll); h[0]=hh; l[0]=ll;
    split_f32(f0.y, hh, ll); h[1]=hh; l[1]=ll;
    split_f32(f0.z, hh, ll); h[2]=hh; l[2]=ll;
    split_f32(f0.w, hh, ll); h[3]=hh; l[3]=ll;
    split_f32(f1.x, hh, ll); h[4]=hh; l[4]=ll;
    split_f32(f1.y, hh, ll); h[5]=hh; l[5]=ll;
    split_f32(f1.z, hh, ll); h[6]=hh; l[6]=ll;
    split_f32(f1.w, hh, ll); h[7]=hh; l[7]=ll;
    u16* base = mp + (size_t)i*16;
    *(u16x8*)base = h;
    *(u16x8*)(base+8) = l;
  }
}

__global__ __launch_bounds__(256) void copy_kernel(const float4* __restrict__ src,
                                                   float4* __restrict__ dst, int n4)
{
  int i = blockIdx.x*256 + threadIdx.x;
  const int stride = gridDim.x*256;
  for (; i < n4; i += stride) dst[i] = src[i];
}

__global__ __launch_bounds__(128) void update_kernel(const float* __restrict__ mem,
    const float* __restrict__ v2, const int* __restrict__ y, float* __restrict__ outmem)
{
  const int b = blockIdx.x;
  const int t = threadIdx.x;
  const int row = y[b];
  for (int b2=b+1; b2<64; ++b2) if (y[b2] == row) return;   // later duplicate wins
  float ab = 0.5f*mem[(size_t)row*128 + t] + 0.5f*v2[b*128 + t];
  __shared__ float red[2];
  float s = ab*ab;
  #pragma unroll
  for (int off=1; off<64; off<<=1) s += __shfl_xor(s, off, 64);
  if ((t & 63) == 0) red[t>>6] = s;
  __syncthreads();
  float tot = red[0] + red[1];
  outmem[(size_t)row*128 + t] = ab / sqrtf(tot);
}

// scores wss[b][s] -> out[s][b]
__global__ __launch_bounds__(256) void transpose_kernel(const float* __restrict__ wss,
                                                        float* __restrict__ out)
{
  __shared__ float tile[64][65];
  const int t = blockIdx.x;
  const int c = threadIdx.x & 63;
  const int r4 = threadIdx.x >> 6;
  #pragma unroll
  for (int i=0;i<16;i++){
    int bb = i*4 + r4;
    tile[bb][c] = wss[(size_t)bb*4096 + t*64 + c];
  }
  __syncthreads();
  #pragma unroll
  for (int i=0;i<16;i++){
    int s = i*4 + r4;
    out[(size_t)(t*64+s)*64 + c] = tile[c][s];
  }
}

extern "C" void kernel_launch(void* const* d_in, const int* in_sizes, int n_in,
                              void* d_out, int out_size, void* d_ws, size_t ws_size,
                              hipStream_t stream) {
  (void)in_sizes; (void)n_in; (void)out_size;
  const float* v1      = (const float*)d_in[0];
  const float* v2      = (const float*)d_in[1];
  const float* mem     = (const float*)d_in[2];
  const float* mt_w1   = (const float*)d_in[3];
  const float* mt_b1   = (const float*)d_in[4];
  const float* mt_w2   = (const float*)d_in[5];
  const float* mt_b2   = (const float*)d_in[6];
  const float* mt_wv   = (const float*)d_in[7];
  const float* mt_bv   = (const float*)d_in[8];
  const float* mts_w1  = (const float*)d_in[9];
  const float* mts_b1  = (const float*)d_in[10];
  const float* mts_w2  = (const float*)d_in[11];
  const float* mts_b2  = (const float*)d_in[12];
  const float* mts_wv  = (const float*)d_in[13];
  const float* mts_bv  = (const float*)d_in[14];
  const float* ht_w    = (const float*)d_in[15];
  const float* ht_b    = (const float*)d_in[16];
  const float* hts_w   = (const float*)d_in[17];
  const float* hts_b   = (const float*)d_in[18];
  const int*   y       = (const int*)d_in[19];
  const int*   idx     = (const int*)d_in[20];
  float* out = (float*)d_out;
  float* outmem = out + 262144;
  char* ws = (char*)d_ws;

  u16* w2a = (u16*)(ws + 0);
  u16* w2b = (u16*)(ws + 65536);
  u16* wc1 = (u16*)(ws + 131072);
  u16* wc2 = (u16*)(ws + 196608);
  float* c1   = (float*)(ws + 262144);
  float* c2   = (float*)(ws + 294912);
  float* bc1  = (float*)(ws + 327680);
  float* bc2  = (float*)(ws + 328192);
  float* wss  = (float*)(ws + 393216);   // 64*4096 f32 = 1MB

  const size_t PLANES_OFF = 2097152;
  const size_t PLANES_BYTES = (size_t)100000 * 512;   // 51.2MB interleaved hi|lo
  const bool bigws = ws_size >= PLANES_OFF + PLANES_BYTES;
  u16* mp = bigws ? (u16*)(ws + PLANES_OFF) : (u16*)outmem;  // fallback parks plane in outmem

  // 1. split bank to interleaved plane (+ fused copy when plane doesn't alias outmem)
  split_copy_kernel<<<2048, 256, 0, stream>>>((const float4*)mem, (float4*)outmem,
                                              mp, 1600000, bigws ? 1 : 0);
  // 2. weights/c/bc prep
  prep_kernel<<<512, 128, 0, stream>>>(v1, v2,
      mt_w1, mt_b1, mt_w2, mt_b2, mt_wv, mt_bv,
      mts_w1, mts_b1, mts_w2, mts_b2, mts_wv, mts_bv,
      ht_w, ht_b, hts_w, hts_b,
      w2a, w2b, wc1, wc2, c1, c2, bc1, bc2);
  // 3. main fused compute -> wss
  main_kernel<<<dim3(8, 64), 256, 0, stream>>>(mp, idx,
      w2a, w2b, wc1, wc2, c1, c2, bc1, bc2, wss);
  // 4. new_memory
  if (!bigws)
    copy_kernel<<<2048, 256, 0, stream>>>((const float4*)mem, (float4*)outmem, 3200000);
  update_kernel<<<64, 128, 0, stream>>>(mem, v2, y, outmem);
  // 5. scores transpose into out
  transpose_kernel<<<64, 256, 0, stream>>>(wss, out);
}

// Round 6
// 262.359 us; speedup vs baseline: 1.0495x; 1.0495x over previous
//
#include <hip/hip_runtime.h>

typedef __attribute__((ext_vector_type(8))) short bf16x8;
typedef __attribute__((ext_vector_type(4))) float f32x4;
typedef __attribute__((ext_vector_type(4))) unsigned short u16x4;
typedef __attribute__((ext_vector_type(8))) unsigned short u16x8;
typedef unsigned short u16;
typedef unsigned int u32;

#define MFMA16(a,b,c) __builtin_amdgcn_mfma_f32_16x16x32_bf16(a,b,c,0,0,0)

// ---------- f32 -> (bf16 hi, bf16 lo) split ----------
// hi = truncate-to-bf16; lo = bf16(x - hi). 3-product MFMA ~ fp32-class accuracy.
__device__ __forceinline__ void split_f32(float x, u16 &hi, u16 &lo){
  unsigned u = __float_as_uint(x);
  unsigned hif = u & 0xFFFF0000u;
  float rest = x - __uint_as_float(hif);
  hi = (u16)(u >> 16);
  lo = (u16)(__float_as_uint(rest) >> 16);
}

__device__ __forceinline__ void gload_lds16(const void* g, void* l){
  __builtin_amdgcn_global_load_lds((const __attribute__((address_space(1))) u32*)g,
                                   (__attribute__((address_space(3))) u32*)l, 16, 0, 0);
}

// Weight frag sets (per k-step), explicit 1-deep double buffer.
struct DFrag { bf16x8 ah[2], al[2], bh[2], bl[2]; };   // dual-matrix: 8 b128 = 32 VGPR
struct SFrag { bf16x8 h[2], l[2]; };                   // single: 4 b128 = 16 VGPR

__device__ __forceinline__ void load_dual_k(const u16* __restrict__ wa, const u16* __restrict__ wb,
                                            int rowbase, int k, DFrag &F){
  #pragma unroll
  for (int mm=0;mm<2;mm++){
    F.ah[mm] = *(const bf16x8*)(wa + rowbase + mm*4096 + k*64);
    F.bh[mm] = *(const bf16x8*)(wb + rowbase + mm*4096 + k*64);
    F.al[mm] = *(const bf16x8*)(wa + rowbase + mm*4096 + k*64 + 8);
    F.bl[mm] = *(const bf16x8*)(wb + rowbase + mm*4096 + k*64 + 8);
  }
}
__device__ __forceinline__ void load_one_k(const u16* __restrict__ w, int rowbase, int k, SFrag &F){
  #pragma unroll
  for (int mm=0;mm<2;mm++){
    F.h[mm] = *(const bf16x8*)(w + rowbase + mm*4096 + k*64);
    F.l[mm] = *(const bf16x8*)(w + rowbase + mm*4096 + k*64 + 8);
  }
}

// consume one k-step: LDS B-frags (M or pre planes) x weight frags -> acc
__device__ __forceinline__ void mfma_dual_k(const DFrag &F, const u16* ldsHi, const u16* ldsLo,
    f32x4 acc1[2][4], f32x4 acc2[2][4], int k, int lg, int li){
  __builtin_amdgcn_s_setprio(1);
  #pragma unroll
  for (int n=0;n<4;n++){
    const int row = n*16 + li;
    const int a = row*128 + (((k*4+lg) ^ li)<<3);
    bf16x8 bh = *(const bf16x8*)(ldsHi + a);
    bf16x8 bl = *(const bf16x8*)(ldsLo + a);
    #pragma unroll
    for (int mm=0;mm<2;mm++){
      acc1[mm][n] = MFMA16(F.ah[mm], bh, acc1[mm][n]);
      acc2[mm][n] = MFMA16(F.bh[mm], bh, acc2[mm][n]);
      acc1[mm][n] = MFMA16(F.ah[mm], bl, acc1[mm][n]);
      acc2[mm][n] = MFMA16(F.bh[mm], bl, acc2[mm][n]);
      acc1[mm][n] = MFMA16(F.al[mm], bh, acc1[mm][n]);
      acc2[mm][n] = MFMA16(F.bl[mm], bh, acc2[mm][n]);
    }
  }
  __builtin_amdgcn_s_setprio(0);
}
__device__ __forceinline__ void mfma_one_k(const SFrag &F, const u16* ldsHi, const u16* ldsLo,
    f32x4 acc[2][4], int k, int lg, int li){
  __builtin_amdgcn_s_setprio(1);
  #pragma unroll
  for (int n=0;n<4;n++){
    const int row = n*16 + li;
    const int a = row*128 + (((k*4+lg) ^ li)<<3);
    bf16x8 bh = *(const bf16x8*)(ldsHi + a);
    bf16x8 bl = *(const bf16x8*)(ldsLo + a);
    #pragma unroll
    for (int mm=0;mm<2;mm++){
      acc[mm][n] = MFMA16(F.h[mm], bh, acc[mm][n]);
      acc[mm][n] = MFMA16(F.h[mm], bl, acc[mm][n]);
      acc[mm][n] = MFMA16(F.l[mm], bh, acc[mm][n]);
    }
  }
  __builtin_amdgcn_s_setprio(0);
}

// pre[s][d'] = relu(c[d'] - T[d'][s]) -> LDS planes, b64 along d'
__device__ __forceinline__ void write_pre(u16* ldsHi, u16* ldsLo,
    const f32x4 acc[2][4], const float4 cv[2], int wid, int lg, int li)
{
  #pragma unroll
  for (int mm=0;mm<2;mm++){
    const int g = wid*8 + mm*4 + lg;
    #pragma unroll
    for (int n=0;n<4;n++){
      const int row = n*16 + li;
      u16x4 h4, l4;
      #pragma unroll
      for (int r=0;r<4;r++){
        float cr = (r==0)?cv[mm].x:(r==1)?cv[mm].y:(r==2)?cv[mm].z:cv[mm].w;
        float p = fmaxf(cr - acc[mm][n][r], 0.f);
        u16 hh, ll; split_f32(p, hh, ll);
        h4[r] = hh; l4[r] = ll;
      }
      const int a = row*128 + (((g>>1) ^ li)<<3) + ((g&1)<<2);
      *(u16x4*)&ldsHi[a] = h4;
      *(u16x4*)&ldsLo[a] = l4;
    }
  }
}

// ---------- prep: c vectors, folded Wc = hw@wv, bc = hw@bv+hb, W2 split+interleave ----------
__global__ __launch_bounds__(128) void prep_kernel(
    const float* __restrict__ v1, const float* __restrict__ v2,
    const float* __restrict__ mt_w1, const float* __restrict__ mt_b1,
    const float* __restrict__ mt_w2, const float* __restrict__ mt_b2,
    const float* __restrict__ mt_wv, const float* __restrict__ mt_bv,
    const float* __restrict__ mts_w1, const float* __restrict__ mts_b1,
    const float* __restrict__ mts_w2, const float* __restrict__ mts_b2,
    const float* __restrict__ mts_wv, const float* __restrict__ mts_bv,
    const float* __restrict__ ht_w, const float* __restrict__ ht_b,
    const float* __restrict__ hts_w, const float* __restrict__ hts_b,
    u16* __restrict__ w2a, u16* __restrict__ w2b,
    u16* __restrict__ wc1, u16* __restrict__ wc2,
    float* __restrict__ c1, float* __restrict__ c2,
    float* __restrict__ bc1, float* __restrict__ bc2)
{
  const int blk = blockIdx.x;
  const int t = threadIdx.x;   // 128 threads
  if (blk < 128) {
    const bool second = blk >= 64;
    const int b = blk & 63;
    const float* x  = second ? v1 : v2;
    const float* w1 = second ? mts_w1 : mt_w1;
    const float* b1 = second ? mts_b1 : mt_b1;
    const float* b2 = second ? mts_b2 : mt_b2;
    float* c = second ? c2 : c1;
    __shared__ float xr[128];
    xr[t] = x[b*128 + t];
    __syncthreads();
    float s = 0.f;
    #pragma unroll 8
    for (int k=0;k<128;k++) s += w1[t*128 + k] * xr[k];
    c[b*128 + t] = s + b1[t] - b2[t];
  } else if (blk < 384) {
    const bool second = blk >= 256;
    const int e = blk - (second ? 256 : 128);
    const float* hw = second ? hts_w : ht_w;
    const float* wv = second ? mts_wv : mt_wv;
    const float* bv = second ? mts_bv : mt_bv;
    const float* hb = second ? hts_b : ht_b;
    u16* wc = second ? wc2 : wc1;
    float* bcp = second ? bc2 : bc1;
    float s = 0.f;
    #pragma unroll 8
    for (int k=0;k<128;k++) s += hw[e*128 + k] * wv[k*128 + t];
    u16 hi, lo; split_f32(s, hi, lo);
    int oi = e*256 + ((t>>3)<<4) + (t&7);
    wc[oi] = hi; wc[oi+8] = lo;
    __shared__ float red[128];
    red[t] = hw[e*128 + t] * bv[t];
    __syncthreads();
    for (int off=64; off>0; off>>=1){ if (t<off) red[t] += red[t+off]; __syncthreads(); }
    if (t==0) bcp[e] = red[0] + hb[e];
  } else {
    const int i = (blk-384)*128 + t;
    const int r = i >> 7, col = i & 127;
    const int oi = r*256 + ((col>>3)<<4) + (col&7);
    u16 hi, lo;
    split_f32(mt_w2[i], hi, lo);  w2a[oi] = hi; w2a[oi+8] = lo;
    split_f32(mts_w2[i], hi, lo); w2b[oi] = hi; w2b[oi+8] = lo;
  }
}

// ---------- main: persistent 768 blocks (3/CU), grid-stride over 4096 (b x stile) tiles ----------
__global__ __launch_bounds__(256, 3) void main_kernel(
    const u16* __restrict__ mh, const u16* __restrict__ ml,
    const int* __restrict__ idx,
    const u16* __restrict__ w2a, const u16* __restrict__ w2b,
    const u16* __restrict__ wc1, const u16* __restrict__ wc2,
    const float* __restrict__ c1, const float* __restrict__ c2,
    const float* __restrict__ bc1, const float* __restrict__ bc2,
    float* __restrict__ wss)
{
  __shared__ u16 ldsHi[64*128];      // 16KB
  __shared__ u16 ldsLo[64*128];      // 16KB
  __shared__ float part[4][64][3];   // 3KB

  const int tid = threadIdx.x;
  const int wid = tid >> 6;
  const int lane = tid & 63;
  const int lg = lane >> 4, li = lane & 15;
  const int rowbase = (wid*32 + li)*256 + lg*16;

  // loop-invariant biases
  float4 b1v[2], b2v[2];
  #pragma unroll
  for (int mm=0;mm<2;mm++){
    b1v[mm] = *(const float4*)(bc1 + wid*32 + mm*16 + lg*4);
    b2v[mm] = *(const float4*)(bc2 + wid*32 + mm*16 + lg*4);
  }

  for (int T = blockIdx.x; T < 4096; T += gridDim.x){
    const int b = T >> 6;
    const int s0 = (T & 63) * 64;

    // stage: wave wid stages rows wid*16..+16 from pre-split planes via global_load_lds
    {
      const int q = lane >> 4;
      const int sl = lane & 15;
      #pragma unroll
      for (int i=0;i<4;i++){
        const int rloc = i*4 + q;
        const int row  = wid*16 + rloc;
        const int ridx = idx[b*4096 + s0 + row];
        const int srcslot = sl ^ rloc;
        const size_t soff = (size_t)ridx*128 + srcslot*8;
        gload_lds16(mh + soff, &ldsHi[(wid*16 + i*4)*128]);
        gload_lds16(ml + soff, &ldsLo[(wid*16 + i*4)*128]);
      }
    }

    // GEMM1 k=0 weight frags: issued BEFORE the gather barrier (overlap gather latency)
    DFrag Fd[2];
    load_dual_k(w2a, w2b, rowbase, 0, Fd[0]);
    __syncthreads();   // gather + k0 frags complete

    f32x4 acc1[2][4], acc2[2][4];
    #pragma unroll
    for (int mm=0;mm<2;mm++)
      #pragma unroll
      for (int n=0;n<4;n++){ acc1[mm][n]=(f32x4)(0.f); acc2[mm][n]=(f32x4)(0.f); }

    // GEMM1 dual: T1^T, T2^T with full 1-deep hi+lo prefetch
    #pragma unroll
    for (int k=0;k<4;k++){
      if (k<3) load_dual_k(w2a, w2b, rowbase, k+1, Fd[(k+1)&1]);
      mfma_dual_k(Fd[k&1], ldsHi, ldsLo, acc1, acc2, k, lg, li);
    }

    // early-issue GEMM2 k0 frags + c1 vector (fly during barrier + pre-write + barrier)
    SFrag Fs[2];
    load_one_k(wc1, rowbase, 0, Fs[0]);
    float4 cv1[2], cv2[2];
    #pragma unroll
    for (int mm=0;mm<2;mm++) cv1[mm] = *(const float4*)(c1 + b*128 + wid*32 + mm*16 + lg*4);
    __syncthreads();                                       // M reads done

    write_pre(ldsHi, ldsLo, acc1, cv1, wid, lg, li);       // pre1 -> planes
    __syncthreads();                                       // pre1 visible

    f32x4 h1[2][4];
    #pragma unroll
    for (int mm=0;mm<2;mm++)
      #pragma unroll
      for (int n=0;n<4;n++) h1[mm][n]=(f32x4)(0.f);
    #pragma unroll
    for (int k=0;k<4;k++){
      if (k<3) load_one_k(wc1, rowbase, k+1, Fs[(k+1)&1]);
      mfma_one_k(Fs[k&1], ldsHi, ldsLo, h1, k, lg, li);
    }

    // early-issue GEMM3 k0 frags + c2 vector
    load_one_k(wc2, rowbase, 0, Fs[0]);
    #pragma unroll
    for (int mm=0;mm<2;mm++) cv2[mm] = *(const float4*)(c2 + b*128 + wid*32 + mm*16 + lg*4);
    __syncthreads();                                       // pre1 reads done

    write_pre(ldsHi, ldsLo, acc2, cv2, wid, lg, li);       // pre2 -> planes
    __syncthreads();                                       // pre2 visible

    f32x4 h2[2][4];
    #pragma unroll
    for (int mm=0;mm<2;mm++)
      #pragma unroll
      for (int n=0;n<4;n++) h2[mm][n]=(f32x4)(0.f);
    #pragma unroll
    for (int k=0;k<4;k++){
      if (k<3) load_one_k(wc2, rowbase, k+1, Fs[(k+1)&1]);
      mfma_one_k(Fs[k&1], ldsHi, ldsLo, h2, k, lg, li);
    }

    // score partials: lane holds h[e'][s], e' = wid*32+mm*16+lg*4+r, s = n*16+li
    #pragma unroll
    for (int n=0;n<4;n++){
      float p11=0.f, p22=0.f, p12=0.f;
      #pragma unroll
      for (int mm=0;mm<2;mm++){
        #pragma unroll
        for (int r=0;r<4;r++){
          float bb1 = (r==0)?b1v[mm].x:(r==1)?b1v[mm].y:(r==2)?b1v[mm].z:b1v[mm].w;
          float bb2 = (r==0)?b2v[mm].x:(r==1)?b2v[mm].y:(r==2)?b2v[mm].z:b2v[mm].w;
          float v1h = h1[mm][n][r] + bb1;
          float v2h = h2[mm][n][r] + bb2;
          p11 += v1h*v1h; p22 += v2h*v2h; p12 += v1h*v2h;
        }
      }
      p11 += __shfl_xor(p11, 16, 64); p11 += __shfl_xor(p11, 32, 64);
      p22 += __shfl_xor(p22, 16, 64); p22 += __shfl_xor(p22, 32, 64);
      p12 += __shfl_xor(p12, 16, 64); p12 += __shfl_xor(p12, 32, 64);
      if (lane < 16){
        part[wid][n*16+li][0] = p11;
        part[wid][n*16+li][1] = p22;
        part[wid][n*16+li][2] = p12;
      }
    }
    __syncthreads();   // partials visible; also fences all GEMM3 plane reads before next stage
    if (tid < 64){
      float S11 = part[0][tid][0] + part[1][tid][0] + part[2][tid][0] + part[3][tid][0];
      float S22 = part[0][tid][1] + part[1][tid][1] + part[2][tid][1] + part[3][tid][1];
      float S12 = part[0][tid][2] + part[1][tid][2] + part[2][tid][2] + part[3][tid][2];
      float dot = S12 / sqrtf(S11 * S22);
      wss[(size_t)b*4096 + s0 + tid] = expf((dot - 1.0f) * (1.0f/0.07f));
    }
    __syncthreads();   // part reads done before next tile overwrites
  }
}

// ---------- split (+ optional copy): bank -> hi/lo planes ----------
__global__ __launch_bounds__(256) void split_copy_kernel(const float4* __restrict__ src,
    float4* __restrict__ dst, u16x4* __restrict__ mh, u16x4* __restrict__ ml,
    int n4, int docopy)
{
  int i = blockIdx.x*256 + threadIdx.x;
  const int stride = gridDim.x*256;
  for (; i < n4; i += stride){
    float4 f = src[i];
    if (docopy) dst[i] = f;
    u16x4 h, l; u16 hh, ll;
    split_f32(f.x, hh, ll); h[0]=hh; l[0]=ll;
    split_f32(f.y, hh, ll); h[1]=hh; l[1]=ll;
    split_f32(f.z, hh, ll); h[2]=hh; l[2]=ll;
    split_f32(f.w, hh, ll); h[3]=hh; l[3]=ll;
    mh[i] = h; ml[i] = l;
  }
}

__global__ __launch_bounds__(256) void copy_kernel(const float4* __restrict__ src,
                                                   float4* __restrict__ dst, int n4)
{
  int i = blockIdx.x*256 + threadIdx.x;
  const int stride = gridDim.x*256;
  for (; i < n4; i += stride) dst[i] = src[i];
}

__global__ __launch_bounds__(128) void update_kernel(const float* __restrict__ mem,
    const float* __restrict__ v2, const int* __restrict__ y, float* __restrict__ outmem)
{
  const int b = blockIdx.x;
  const int t = threadIdx.x;
  const int row = y[b];
  for (int b2=b+1; b2<64; ++b2) if (y[b2] == row) return;   // later duplicate wins
  float ab = 0.5f*mem[(size_t)row*128 + t] + 0.5f*v2[b*128 + t];
  __shared__ float red[2];
  float s = ab*ab;
  #pragma unroll
  for (int off=1; off<64; off<<=1) s += __shfl_xor(s, off, 64);
  if ((t & 63) == 0) red[t>>6] = s;
  __syncthreads();
  float tot = red[0] + red[1];
  outmem[(size_t)row*128 + t] = ab / sqrtf(tot);
}

// scores wss[b][s] -> out[s][b]
__global__ __launch_bounds__(256) void transpose_kernel(const float* __restrict__ wss,
                                                        float* __restrict__ out)
{
  __shared__ float tile[64][65];
  const int t = blockIdx.x;
  const int c = threadIdx.x & 63;
  const int r4 = threadIdx.x >> 6;
  #pragma unroll
  for (int i=0;i<16;i++){
    int bb = i*4 + r4;
    tile[bb][c] = wss[(size_t)bb*4096 + t*64 + c];
  }
  __syncthreads();
  #pragma unroll
  for (int i=0;i<16;i++){
    int s = i*4 + r4;
    out[(size_t)(t*64+s)*64 + c] = tile[c][s];
  }
}

extern "C" void kernel_launch(void* const* d_in, const int* in_sizes, int n_in,
                              void* d_out, int out_size, void* d_ws, size_t ws_size,
                              hipStream_t stream) {
  (void)in_sizes; (void)n_in; (void)out_size;
  const float* v1      = (const float*)d_in[0];
  const float* v2      = (const float*)d_in[1];
  const float* mem     = (const float*)d_in[2];
  const float* mt_w1   = (const float*)d_in[3];
  const float* mt_b1   = (const float*)d_in[4];
  const float* mt_w2   = (const float*)d_in[5];
  const float* mt_b2   = (const float*)d_in[6];
  const float* mt_wv   = (const float*)d_in[7];
  const float* mt_bv   = (const float*)d_in[8];
  const float* mts_w1  = (const float*)d_in[9];
  const float* mts_b1  = (const float*)d_in[10];
  const float* mts_w2  = (const float*)d_in[11];
  const float* mts_b2  = (const float*)d_in[12];
  const float* mts_wv  = (const float*)d_in[13];
  const float* mts_bv  = (const float*)d_in[14];
  const float* ht_w    = (const float*)d_in[15];
  const float* ht_b    = (const float*)d_in[16];
  const float* hts_w   = (const float*)d_in[17];
  const float* hts_b   = (const float*)d_in[18];
  const int*   y       = (const int*)d_in[19];
  const int*   idx     = (const int*)d_in[20];
  float* out = (float*)d_out;
  float* outmem = out + 262144;
  char* ws = (char*)d_ws;

  u16* w2a = (u16*)(ws + 0);
  u16* w2b = (u16*)(ws + 65536);
  u16* wc1 = (u16*)(ws + 131072);
  u16* wc2 = (u16*)(ws + 196608);
  float* c1   = (float*)(ws + 262144);
  float* c2   = (float*)(ws + 294912);
  float* bc1  = (float*)(ws + 327680);
  float* bc2  = (float*)(ws + 328192);
  float* wss  = (float*)(ws + 393216);   // 64*4096 f32 = 1MB

  const size_t PLANES_OFF = 2097152;
  const size_t PLANES_BYTES = (size_t)12800000 * 2 * 2;   // 51.2MB
  const bool bigws = ws_size >= PLANES_OFF + PLANES_BYTES;
  u16 *mh, *ml;
  if (bigws){ mh = (u16*)(ws + PLANES_OFF); }
  else      { mh = (u16*)outmem; }            // park planes in new_memory region
  ml = mh + 12800000;

  // 1. split bank to hi/lo planes (+ fused copy when planes don't alias outmem)
  split_copy_kernel<<<2048, 256, 0, stream>>>((const float4*)mem, (float4*)outmem,
                                              (u16x4*)mh, (u16x4*)ml, 3200000, bigws ? 1 : 0);
  // 2. weights/c/bc prep
  prep_kernel<<<512, 128, 0, stream>>>(v1, v2,
      mt_w1, mt_b1, mt_w2, mt_b2, mt_wv, mt_bv,
      mts_w1, mts_b1, mts_w2, mts_b2, mts_wv, mts_bv,
      ht_w, ht_b, hts_w, hts_b,
      w2a, w2b, wc1, wc2, c1, c2, bc1, bc2);
  // 3. main fused compute -> wss (persistent: 768 blocks = 3/CU resident)
  main_kernel<<<768, 256, 0, stream>>>(mh, ml, idx,
      w2a, w2b, wc1, wc2, c1, c2, bc1, bc2, wss);
  // 4. new_memory
  if (!bigws)
    copy_kernel<<<2048, 256, 0, stream>>>((const float4*)mem, (float4*)outmem, 3200000);
  update_kernel<<<64, 128, 0, stream>>>(mem, v2, y, outmem);
  // 5. scores transpose into out
  transpose_kernel<<<64, 256, 0, stream>>>(wss, out);
}

// Round 7
// 164.605 us; speedup vs baseline: 1.6728x; 1.5939x over previous
//
#include <hip/hip_runtime.h>

typedef __attribute__((ext_vector_type(8))) short bf16x8;
typedef __attribute__((ext_vector_type(4))) float f32x4;
typedef __attribute__((ext_vector_type(4))) unsigned short u16x4;
typedef unsigned short u16;
typedef unsigned int u32;

#define MFMA16(a,b,c) __builtin_amdgcn_mfma_f32_16x16x32_bf16(a,b,c,0,0,0)

// ---------- f32 -> (bf16 hi, bf16 lo) split ----------
// hi = truncate-to-bf16; lo = bf16(x - hi). 3-product MFMA ~ fp32-class accuracy.
__device__ __forceinline__ void split_f32(float x, u16 &hi, u16 &lo){
  unsigned u = __float_as_uint(x);
  unsigned hif = u & 0xFFFF0000u;
  float rest = x - __uint_as_float(hif);
  hi = (u16)(u >> 16);
  lo = (u16)(__float_as_uint(rest) >> 16);
}

__device__ __forceinline__ void gload_lds16(const void* g, void* l){
  __builtin_amdgcn_global_load_lds((const __attribute__((address_space(1))) u32*)g,
                                   (__attribute__((address_space(3))) u32*)l, 16, 0, 0);
}

// ---------- prep: c vectors, folded Wc = hw@wv, bc = hw@bv+hb, W2 split+interleave ----------
__global__ __launch_bounds__(128) void prep_kernel(
    const float* __restrict__ v1, const float* __restrict__ v2,
    const float* __restrict__ mt_w1, const float* __restrict__ mt_b1,
    const float* __restrict__ mt_w2, const float* __restrict__ mt_b2,
    const float* __restrict__ mt_wv, const float* __restrict__ mt_bv,
    const float* __restrict__ mts_w1, const float* __restrict__ mts_b1,
    const float* __restrict__ mts_w2, const float* __restrict__ mts_b2,
    const float* __restrict__ mts_wv, const float* __restrict__ mts_bv,
    const float* __restrict__ ht_w, const float* __restrict__ ht_b,
    const float* __restrict__ hts_w, const float* __restrict__ hts_b,
    u16* __restrict__ w2a, u16* __restrict__ w2b,
    u16* __restrict__ wc1, u16* __restrict__ wc2,
    float* __restrict__ c1, float* __restrict__ c2,
    float* __restrict__ bc1, float* __restrict__ bc2)
{
  const int blk = blockIdx.x;
  const int t = threadIdx.x;   // 128 threads
  if (blk < 128) {
    const bool second = blk >= 64;
    const int b = blk & 63;
    const float* x  = second ? v1 : v2;
    const float* w1 = second ? mts_w1 : mt_w1;
    const float* b1 = second ? mts_b1 : mt_b1;
    const float* b2 = second ? mts_b2 : mt_b2;
    float* c = second ? c2 : c1;
    __shared__ float xr[128];
    xr[t] = x[b*128 + t];
    __syncthreads();
    float s = 0.f;
    #pragma unroll 8
    for (int k=0;k<128;k++) s += w1[t*128 + k] * xr[k];
    c[b*128 + t] = s + b1[t] - b2[t];
  } else if (blk < 384) {
    const bool second = blk >= 256;
    const int e = blk - (second ? 256 : 128);
    const float* hw = second ? hts_w : ht_w;
    const float* wv = second ? mts_wv : mt_wv;
    const float* bv = second ? mts_bv : mt_bv;
    const float* hb = second ? hts_b : ht_b;
    u16* wc = second ? wc2 : wc1;
    float* bcp = second ? bc2 : bc1;
    float s = 0.f;
    #pragma unroll 8
    for (int k=0;k<128;k++) s += hw[e*128 + k] * wv[k*128 + t];
    u16 hi, lo; split_f32(s, hi, lo);
    int oi = e*256 + ((t>>3)<<4) + (t&7);
    wc[oi] = hi; wc[oi+8] = lo;
    __shared__ float red[128];
    red[t] = hw[e*128 + t] * bv[t];
    __syncthreads();
    for (int off=64; off>0; off>>=1){ if (t<off) red[t] += red[t+off]; __syncthreads(); }
    if (t==0) bcp[e] = red[0] + hb[e];
  } else {
    const int i = (blk-384)*128 + t;
    const int r = i >> 7, col = i & 127;
    const int oi = r*256 + ((col>>3)<<4) + (col&7);
    u16 hi, lo;
    split_f32(mt_w2[i], hi, lo);  w2a[oi] = hi; w2a[oi+8] = lo;
    split_f32(mts_w2[i], hi, lo); w2b[oi] = hi; w2b[oi+8] = lo;
  }
}

// ---------- main: 1024 blocks x 512 thr (1 block/CU), 4 tiles each, reg-resident weights ----------
__global__ __launch_bounds__(512, 2) void main_kernel(
    const u16* __restrict__ mh, const u16* __restrict__ ml,
    const int* __restrict__ idx,
    const u16* __restrict__ w2a, const u16* __restrict__ w2b,
    const u16* __restrict__ wc1, const u16* __restrict__ wc2,
    const float* __restrict__ c1, const float* __restrict__ c2,
    const float* __restrict__ bc1, const float* __restrict__ bc2,
    float* __restrict__ wss)
{
  __shared__ u16 MhB[2][64*128];   // M double buffer, hi plane (16KB each)
  __shared__ u16 MlB[2][64*128];   // lo plane
  __shared__ u16 P1h[64*128], P1l[64*128];   // pre1 planes
  __shared__ u16 P2h[64*128], P2l[64*128];   // pre2 planes
  __shared__ float part[8][64][3];

  const int tid  = threadIdx.x;
  const int wid  = tid >> 6;        // 0..7 -> d' slice [wid*16, wid*16+16)
  const int lane = tid & 63;
  const int lg = lane >> 4, li = lane & 15;

  // ---- prologue: weights -> registers (row d'=wid*16+li, chunk k*4+lg, 8hi|8lo) ----
  const int wbase = (wid*16 + li)*256 + lg*16;
  bf16x8 W2aH[4], W2aL[4], W2bH[4], W2bL[4], VcaH[4], VcaL[4], VcbH[4], VcbL[4];
  #pragma unroll
  for (int k=0;k<4;k++){
    W2aH[k] = *(const bf16x8*)(w2a + wbase + k*64);
    W2aL[k] = *(const bf16x8*)(w2a + wbase + k*64 + 8);
    W2bH[k] = *(const bf16x8*)(w2b + wbase + k*64);
    W2bL[k] = *(const bf16x8*)(w2b + wbase + k*64 + 8);
    VcaH[k] = *(const bf16x8*)(wc1 + wbase + k*64);
    VcaL[k] = *(const bf16x8*)(wc1 + wbase + k*64 + 8);
    VcbH[k] = *(const bf16x8*)(wc2 + wbase + k*64);
    VcbL[k] = *(const bf16x8*)(wc2 + wbase + k*64 + 8);
  }
  const float4 bb1 = *(const float4*)(bc1 + wid*16 + lg*4);
  const float4 bb2 = *(const float4*)(bc2 + wid*16 + lg*4);

  const int bid = blockIdx.x;      // 1024 blocks; b constant per block
  const int b = bid >> 4;          // 0..63
  const int sbase = (bid & 15) * 256;   // 4 tiles of 64 s each
  const float4 cv1 = *(const float4*)(c1 + b*128 + wid*16 + lg*4);
  const float4 cv2 = *(const float4*)(c2 + b*128 + wid*16 + lg*4);

  // gather roles: wave stages rows [wid*8, wid*8+8); lane q=lane>>4 within 4-row group
  const int q = lane >> 4, sl = lane & 15;

  #define DO_GATHER(I, BUF) {                                            \
    const int s0_ = sbase + (I)*64;                                      \
    _Pragma("unroll")                                                    \
    for (int j=0;j<2;j++){                                               \
      const int grow = wid*8 + j*4 + q;                                  \
      const int ridx = idx[b*4096 + s0_ + grow];                         \
      const size_t soff = (size_t)ridx*128 + (size_t)((sl ^ (grow&15))*8); \
      gload_lds16(mh + soff, &MhB[BUF][(wid*8 + j*4)*128]);              \
      gload_lds16(ml + soff, &MlB[BUF][(wid*8 + j*4)*128]);              \
    }                                                                    \
  }

  DO_GATHER(0, 0);

  for (int i=0; i<4; ++i){
    __syncthreads();              // B1: gather(i) landed; prev pre/part reads done
    const int cur = i & 1;
    if (i < 3) DO_GATHER(i+1, cur^1);

    const u16* mch = MhB[cur];
    const u16* mcl = MlB[cur];

    // ---- GEMM1 dual: T1,T2 [d' x s] from reg weights x LDS M ----
    f32x4 acc1[4], acc2[4];
    #pragma unroll
    for (int n=0;n<4;n++){ acc1[n]=(f32x4)(0.f); acc2[n]=(f32x4)(0.f); }
    #pragma unroll
    for (int k=0;k<4;k++){
      __builtin_amdgcn_s_setprio(1);
      #pragma unroll
      for (int n=0;n<4;n++){
        const int a = (n*16+li)*128 + (((k*4+lg) ^ li)<<3);
        bf16x8 bh = *(const bf16x8*)(mch + a);
        bf16x8 bl = *(const bf16x8*)(mcl + a);
        acc1[n] = MFMA16(W2aH[k], bh, acc1[n]);
        acc2[n] = MFMA16(W2bH[k], bh, acc2[n]);
        acc1[n] = MFMA16(W2aH[k], bl, acc1[n]);
        acc2[n] = MFMA16(W2bH[k], bl, acc2[n]);
        acc1[n] = MFMA16(W2aL[k], bh, acc1[n]);
        acc2[n] = MFMA16(W2bL[k], bh, acc2[n]);
      }
      __builtin_amdgcn_s_setprio(0);
    }

    // ---- pre1/pre2 = relu(c - T) -> pre planes (b64 along d', slot-XOR swizzle) ----
    {
      const int c = wid*2 + (lg>>1);
      const int sub = (lg&1)*4;
      #pragma unroll
      for (int n=0;n<4;n++){
        const int row = n*16 + li;
        const int a = row*128 + ((c ^ li)<<3) + sub;
        u16x4 h4, l4, g4, m4;
        #pragma unroll
        for (int r=0;r<4;r++){
          float c1r = (r==0)?cv1.x:(r==1)?cv1.y:(r==2)?cv1.z:cv1.w;
          float c2r = (r==0)?cv2.x:(r==1)?cv2.y:(r==2)?cv2.z:cv2.w;
          float p1 = fmaxf(c1r - acc1[n][r], 0.f);
          float p2 = fmaxf(c2r - acc2[n][r], 0.f);
          u16 hh, ll;
          split_f32(p1, hh, ll); h4[r]=hh; l4[r]=ll;
          split_f32(p2, hh, ll); g4[r]=hh; m4[r]=ll;
        }
        *(u16x4*)&P1h[a] = h4; *(u16x4*)&P1l[a] = l4;
        *(u16x4*)&P2h[a] = g4; *(u16x4*)&P2l[a] = m4;
      }
    }
    __syncthreads();              // B2: pre planes visible

    // ---- fused GEMM2+GEMM3: h1 = Wc1 x pre1, h2 = Wc2 x pre2 ----
    f32x4 h1[4], h2[4];
    #pragma unroll
    for (int n=0;n<4;n++){ h1[n]=(f32x4)(0.f); h2[n]=(f32x4)(0.f); }
    #pragma unroll
    for (int k=0;k<4;k++){
      __builtin_amdgcn_s_setprio(1);
      #pragma unroll
      for (int n=0;n<4;n++){
        const int a = (n*16+li)*128 + (((k*4+lg) ^ li)<<3);
        bf16x8 p1h = *(const bf16x8*)(P1h + a);
        bf16x8 p1l = *(const bf16x8*)(P1l + a);
        bf16x8 p2h = *(const bf16x8*)(P2h + a);
        bf16x8 p2l = *(const bf16x8*)(P2l + a);
        h1[n] = MFMA16(VcaH[k], p1h, h1[n]);
        h2[n] = MFMA16(VcbH[k], p2h, h2[n]);
        h1[n] = MFMA16(VcaH[k], p1l, h1[n]);
        h2[n] = MFMA16(VcbH[k], p2l, h2[n]);
        h1[n] = MFMA16(VcaL[k], p1h, h1[n]);
        h2[n] = MFMA16(VcbL[k], p2h, h2[n]);
      }
      __builtin_amdgcn_s_setprio(0);
    }

    // ---- score partials: lane holds h[d'][s], d' = wid*16+lg*4+r, s = n*16+li ----
    #pragma unroll
    for (int n=0;n<4;n++){
      float p11=0.f, p22=0.f, p12=0.f;
      #pragma unroll
      for (int r=0;r<4;r++){
        float e1 = (r==0)?bb1.x:(r==1)?bb1.y:(r==2)?bb1.z:bb1.w;
        float e2 = (r==0)?bb2.x:(r==1)?bb2.y:(r==2)?bb2.z:bb2.w;
        float v1h = h1[n][r] + e1;
        float v2h = h2[n][r] + e2;
        p11 += v1h*v1h; p22 += v2h*v2h; p12 += v1h*v2h;
      }
      p11 += __shfl_xor(p11, 16, 64); p11 += __shfl_xor(p11, 32, 64);
      p22 += __shfl_xor(p22, 16, 64); p22 += __shfl_xor(p22, 32, 64);
      p12 += __shfl_xor(p12, 16, 64); p12 += __shfl_xor(p12, 32, 64);
      if (lane < 16){
        part[wid][n*16+li][0] = p11;
        part[wid][n*16+li][1] = p22;
        part[wid][n*16+li][2] = p12;
      }
    }
    __syncthreads();              // B3: partials visible
    if (tid < 64){
      float S11=0.f, S22=0.f, S12=0.f;
      #pragma unroll
      for (int w=0; w<8; w++){
        S11 += part[w][tid][0]; S22 += part[w][tid][1]; S12 += part[w][tid][2];
      }
      float dot = S12 / sqrtf(S11 * S22);
      wss[(size_t)b*4096 + sbase + i*64 + tid] = expf((dot - 1.0f) * (1.0f/0.07f));
    }
  }
  #undef DO_GATHER
}

// ---------- split (+ optional copy): bank -> hi/lo planes ----------
__global__ __launch_bounds__(256) void split_copy_kernel(const float4* __restrict__ src,
    float4* __restrict__ dst, u16x4* __restrict__ mhp, u16x4* __restrict__ mlp,
    int n4, int docopy)
{
  int i = blockIdx.x*256 + threadIdx.x;
  const int stride = gridDim.x*256;
  for (; i < n4; i += stride){
    float4 f = src[i];
    if (docopy) dst[i] = f;
    u16x4 h, l; u16 hh, ll;
    split_f32(f.x, hh, ll); h[0]=hh; l[0]=ll;
    split_f32(f.y, hh, ll); h[1]=hh; l[1]=ll;
    split_f32(f.z, hh, ll); h[2]=hh; l[2]=ll;
    split_f32(f.w, hh, ll); h[3]=hh; l[3]=ll;
    mhp[i] = h; mlp[i] = l;
  }
}

__global__ __launch_bounds__(256) void copy_kernel(const float4* __restrict__ src,
                                                   float4* __restrict__ dst, int n4)
{
  int i = blockIdx.x*256 + threadIdx.x;
  const int stride = gridDim.x*256;
  for (; i < n4; i += stride) dst[i] = src[i];
}

__global__ __launch_bounds__(128) void update_kernel(const float* __restrict__ mem,
    const float* __restrict__ v2, const int* __restrict__ y, float* __restrict__ outmem)
{
  const int b = blockIdx.x;
  const int t = threadIdx.x;
  const int row = y[b];
  for (int b2=b+1; b2<64; ++b2) if (y[b2] == row) return;   // later duplicate wins
  float ab = 0.5f*mem[(size_t)row*128 + t] + 0.5f*v2[b*128 + t];
  __shared__ float red[2];
  float s = ab*ab;
  #pragma unroll
  for (int off=1; off<64; off<<=1) s += __shfl_xor(s, off, 64);
  if ((t & 63) == 0) red[t>>6] = s;
  __syncthreads();
  float tot = red[0] + red[1];
  outmem[(size_t)row*128 + t] = ab / sqrtf(tot);
}

// scores wss[b][s] -> out[s][b]
__global__ __launch_bounds__(256) void transpose_kernel(const float* __restrict__ wss,
                                                        float* __restrict__ out)
{
  __shared__ float tile[64][65];
  const int t = blockIdx.x;
  const int c = threadIdx.x & 63;
  const int r4 = threadIdx.x >> 6;
  #pragma unroll
  for (int i=0;i<16;i++){
    int bb = i*4 + r4;
    tile[bb][c] = wss[(size_t)bb*4096 + t*64 + c];
  }
  __syncthreads();
  #pragma unroll
  for (int i=0;i<16;i++){
    int s = i*4 + r4;
    out[(size_t)(t*64+s)*64 + c] = tile[c][s];
  }
}

extern "C" void kernel_launch(void* const* d_in, const int* in_sizes, int n_in,
                              void* d_out, int out_size, void* d_ws, size_t ws_size,
                              hipStream_t stream) {
  (void)in_sizes; (void)n_in; (void)out_size;
  const float* v1      = (const float*)d_in[0];
  const float* v2      = (const float*)d_in[1];
  const float* mem     = (const float*)d_in[2];
  const float* mt_w1   = (const float*)d_in[3];
  const float* mt_b1   = (const float*)d_in[4];
  const float* mt_w2   = (const float*)d_in[5];
  const float* mt_b2   = (const float*)d_in[6];
  const float* mt_wv   = (const float*)d_in[7];
  const float* mt_bv   = (const float*)d_in[8];
  const float* mts_w1  = (const float*)d_in[9];
  const float* mts_b1  = (const float*)d_in[10];
  const float* mts_w2  = (const float*)d_in[11];
  const float* mts_b2  = (const float*)d_in[12];
  const float* mts_wv  = (const float*)d_in[13];
  const float* mts_bv  = (const float*)d_in[14];
  const float* ht_w    = (const float*)d_in[15];
  const float* ht_b    = (const float*)d_in[16];
  const float* hts_w   = (const float*)d_in[17];
  const float* hts_b   = (const float*)d_in[18];
  const int*   y       = (const int*)d_in[19];
  const int*   idx     = (const int*)d_in[20];
  float* out = (float*)d_out;
  float* outmem = out + 262144;
  char* ws = (char*)d_ws;

  u16* w2a = (u16*)(ws + 0);
  u16* w2b = (u16*)(ws + 65536);
  u16* wc1 = (u16*)(ws + 131072);
  u16* wc2 = (u16*)(ws + 196608);
  float* c1   = (float*)(ws + 262144);
  float* c2   = (float*)(ws + 294912);
  float* bc1  = (float*)(ws + 327680);
  float* bc2  = (float*)(ws + 328192);
  float* wss  = (float*)(ws + 393216);   // 64*4096 f32 = 1MB

  const size_t PLANES_OFF = 2097152;
  const size_t PLANES_BYTES = (size_t)12800000 * 2 * 2;   // 51.2MB
  const bool bigws = ws_size >= PLANES_OFF + PLANES_BYTES;
  u16 *mh, *ml;
  if (bigws){ mh = (u16*)(ws + PLANES_OFF); }
  else      { mh = (u16*)outmem; }            // park planes in new_memory region
  ml = mh + 12800000;

  // 1. split bank to hi/lo planes (+ fused copy when planes don't alias outmem)
  split_copy_kernel<<<2048, 256, 0, stream>>>((const float4*)mem, (float4*)outmem,
                                              (u16x4*)mh, (u16x4*)ml, 3200000, bigws ? 1 : 0);
  // 2. weights/c/bc prep
  prep_kernel<<<512, 128, 0, stream>>>(v1, v2,
      mt_w1, mt_b1, mt_w2, mt_b2, mt_wv, mt_bv,
      mts_w1, mts_b1, mts_w2, mts_b2, mts_wv, mts_bv,
      ht_w, ht_b, hts_w, hts_b,
      w2a, w2b, wc1, wc2, c1, c2, bc1, bc2);
  // 3. main fused compute -> wss (1024 blocks x 512 thr = 1 block/CU, 4 tiles each)
  main_kernel<<<1024, 512, 0, stream>>>(mh, ml, idx,
      w2a, w2b, wc1, wc2, c1, c2, bc1, bc2, wss);
  // 4. new_memory
  if (!bigws)
    copy_kernel<<<2048, 256, 0, stream>>>((const float4*)mem, (float4*)outmem, 3200000);
  update_kernel<<<64, 128, 0, stream>>>(mem, v2, y, outmem);
  // 5. scores transpose into out
  transpose_kernel<<<64, 256, 0, stream>>>(wss, out);
}

// Round 8
// 157.119 us; speedup vs baseline: 1.7525x; 1.0476x over previous
//
#include <hip/hip_runtime.h>

typedef __attribute__((ext_vector_type(8))) short bf16x8;
typedef __attribute__((ext_vector_type(4))) float f32x4;
typedef __attribute__((ext_vector_type(4))) unsigned short u16x4;
typedef unsigned short u16;
typedef unsigned int u32;

#define MFMA16(a,b,c) __builtin_amdgcn_mfma_f32_16x16x32_bf16(a,b,c,0,0,0)

// ---------- f32 -> (bf16 hi, bf16 lo) split ----------
// hi = truncate-to-bf16; lo = bf16(x - hi). 3-product MFMA ~ fp32-class accuracy.
__device__ __forceinline__ void split_f32(float x, u16 &hi, u16 &lo){
  unsigned u = __float_as_uint(x);
  unsigned hif = u & 0xFFFF0000u;
  float rest = x - __uint_as_float(hif);
  hi = (u16)(u >> 16);
  lo = (u16)(__float_as_uint(rest) >> 16);
}

__device__ __forceinline__ void gload_lds16(const void* g, void* l){
  __builtin_amdgcn_global_load_lds((const __attribute__((address_space(1))) u32*)g,
                                   (__attribute__((address_space(3))) u32*)l, 16, 0, 0);
}

// ---------- prep: c vectors, folded Wc = hw@wv, bc = hw@bv+hb, W2 split+interleave ----------
__global__ __launch_bounds__(128) void prep_kernel(
    const float* __restrict__ v1, const float* __restrict__ v2,
    const float* __restrict__ mt_w1, const float* __restrict__ mt_b1,
    const float* __restrict__ mt_w2, const float* __restrict__ mt_b2,
    const float* __restrict__ mt_wv, const float* __restrict__ mt_bv,
    const float* __restrict__ mts_w1, const float* __restrict__ mts_b1,
    const float* __restrict__ mts_w2, const float* __restrict__ mts_b2,
    const float* __restrict__ mts_wv, const float* __restrict__ mts_bv,
    const float* __restrict__ ht_w, const float* __restrict__ ht_b,
    const float* __restrict__ hts_w, const float* __restrict__ hts_b,
    u16* __restrict__ w2a, u16* __restrict__ w2b,
    u16* __restrict__ wc1, u16* __restrict__ wc2,
    float* __restrict__ c1, float* __restrict__ c2,
    float* __restrict__ bc1, float* __restrict__ bc2)
{
  const int blk = blockIdx.x;
  const int t = threadIdx.x;   // 128 threads
  if (blk < 128) {
    const bool second = blk >= 64;
    const int b = blk & 63;
    const float* x  = second ? v1 : v2;
    const float* w1 = second ? mts_w1 : mt_w1;
    const float* b1 = second ? mts_b1 : mt_b1;
    const float* b2 = second ? mts_b2 : mt_b2;
    float* c = second ? c2 : c1;
    __shared__ float xr[128];
    xr[t] = x[b*128 + t];
    __syncthreads();
    float s = 0.f;
    #pragma unroll 8
    for (int k=0;k<128;k++) s += w1[t*128 + k] * xr[k];
    c[b*128 + t] = s + b1[t] - b2[t];
  } else if (blk < 384) {
    const bool second = blk >= 256;
    const int e = blk - (second ? 256 : 128);
    const float* hw = second ? hts_w : ht_w;
    const float* wv = second ? mts_wv : mt_wv;
    const float* bv = second ? mts_bv : mt_bv;
    const float* hb = second ? hts_b : ht_b;
    u16* wc = second ? wc2 : wc1;
    float* bcp = second ? bc2 : bc1;
    float s = 0.f;
    #pragma unroll 8
    for (int k=0;k<128;k++) s += hw[e*128 + k] * wv[k*128 + t];
    u16 hi, lo; split_f32(s, hi, lo);
    int oi = e*256 + ((t>>3)<<4) + (t&7);
    wc[oi] = hi; wc[oi+8] = lo;
    __shared__ float red[128];
    red[t] = hw[e*128 + t] * bv[t];
    __syncthreads();
    for (int off=64; off>0; off>>=1){ if (t<off) red[t] += red[t+off]; __syncthreads(); }
    if (t==0) bcp[e] = red[0] + hb[e];
  } else {
    const int i = (blk-384)*128 + t;
    const int r = i >> 7, col = i & 127;
    const int oi = r*256 + ((col>>3)<<4) + (col&7);
    u16 hi, lo;
    split_f32(mt_w2[i], hi, lo);  w2a[oi] = hi; w2a[oi+8] = lo;
    split_f32(mts_w2[i], hi, lo); w2b[oi] = hi; w2b[oi+8] = lo;
  }
}

// ---------- main: 1024 blocks x 512 thr (1 block/CU), 4 tiles each ----------
// reg-resident weights; idx pre-fetched to registers; raw barriers with counted
// vmcnt so gathers stay in flight across B2/B3 (never drained mid-tile).
__global__ __launch_bounds__(512, 2) void main_kernel(
    const u16* __restrict__ mh, const u16* __restrict__ ml,
    const int* __restrict__ idx,
    const u16* __restrict__ w2a, const u16* __restrict__ w2b,
    const u16* __restrict__ wc1, const u16* __restrict__ wc2,
    const float* __restrict__ c1, const float* __restrict__ c2,
    const float* __restrict__ bc1, const float* __restrict__ bc2,
    float* __restrict__ wss)
{
  __shared__ u16 MhB[2][64*128];   // M double buffer, hi plane (16KB each)
  __shared__ u16 MlB[2][64*128];   // lo plane
  __shared__ u16 P1h[64*128], P1l[64*128];   // pre1 planes
  __shared__ u16 P2h[64*128], P2l[64*128];   // pre2 planes
  __shared__ float part[8][64][3];

  const int tid  = threadIdx.x;
  const int wid  = tid >> 6;        // 0..7 -> d' slice [wid*16, wid*16+16)
  const int lane = tid & 63;
  const int lg = lane >> 4, li = lane & 15;

  // ---- prologue: weights -> registers (row d'=wid*16+li, chunk k*4+lg, 8hi|8lo) ----
  const int wbase = (wid*16 + li)*256 + lg*16;
  bf16x8 W2aH[4], W2aL[4], W2bH[4], W2bL[4], VcaH[4], VcaL[4], VcbH[4], VcbL[4];
  #pragma unroll
  for (int k=0;k<4;k++){
    W2aH[k] = *(const bf16x8*)(w2a + wbase + k*64);
    W2aL[k] = *(const bf16x8*)(w2a + wbase + k*64 + 8);
    W2bH[k] = *(const bf16x8*)(w2b + wbase + k*64);
    W2bL[k] = *(const bf16x8*)(w2b + wbase + k*64 + 8);
    VcaH[k] = *(const bf16x8*)(wc1 + wbase + k*64);
    VcaL[k] = *(const bf16x8*)(wc1 + wbase + k*64 + 8);
    VcbH[k] = *(const bf16x8*)(wc2 + wbase + k*64);
    VcbL[k] = *(const bf16x8*)(wc2 + wbase + k*64 + 8);
  }
  const float4 bb1 = *(const float4*)(bc1 + wid*16 + lg*4);
  const float4 bb2 = *(const float4*)(bc2 + wid*16 + lg*4);

  const int bid = blockIdx.x;      // 1024 blocks; b constant per block
  const int b = bid >> 4;          // 0..63
  const int sbase = (bid & 15) * 256;   // 4 tiles of 64 s each
  const float4 cv1 = *(const float4*)(c1 + b*128 + wid*16 + lg*4);
  const float4 cv2 = *(const float4*)(c2 + b*128 + wid*16 + lg*4);

  // ---- idx prefetch for ALL 4 tiles -> register offsets (no address-dep loads in loop) ----
  const int q = lane >> 4, sl = lane & 15;
  u32 goff[4][2];
  #pragma unroll
  for (int I=0;I<4;I++){
    #pragma unroll
    for (int j=0;j<2;j++){
      const int grow = wid*8 + j*4 + q;
      const int ridx = idx[b*4096 + sbase + I*64 + grow];
      goff[I][j] = (u32)ridx*128 + (u32)((sl ^ (grow&15))*8);
    }
  }

  #define DO_GATHER(I, BUF) {                                  \
    _Pragma("unroll")                                          \
    for (int j=0;j<2;j++){                                     \
      gload_lds16(mh + goff[I][j], &MhB[BUF][(wid*8 + j*4)*128]); \
      gload_lds16(ml + goff[I][j], &MlB[BUF][(wid*8 + j*4)*128]); \
    }                                                          \
  }

  DO_GATHER(0, 0);
  DO_GATHER(1, 1);

  #pragma unroll
  for (int i=0; i<4; ++i){
    // B1: gather(i) landed (leave gather(i+1) in flight); all prev-tile LDS reads fenced at B3
    if (i < 3) asm volatile("s_waitcnt vmcnt(4)" ::: "memory");
    else       asm volatile("s_waitcnt vmcnt(0)" ::: "memory");
    __builtin_amdgcn_s_barrier();
    __builtin_amdgcn_sched_barrier(0);

    const u16* mch = MhB[i&1];
    const u16* mcl = MlB[i&1];

    // ---- GEMM1 dual: T1,T2 [d' x s] from reg weights x LDS M ----
    f32x4 acc1[4], acc2[4];
    #pragma unroll
    for (int n=0;n<4;n++){ acc1[n]=(f32x4)(0.f); acc2[n]=(f32x4)(0.f); }
    #pragma unroll
    for (int k=0;k<4;k++){
      __builtin_amdgcn_s_setprio(1);
      #pragma unroll
      for (int n=0;n<4;n++){
        const int a = (n*16+li)*128 + (((k*4+lg) ^ li)<<3);
        bf16x8 bh = *(const bf16x8*)(mch + a);
        bf16x8 bl = *(const bf16x8*)(mcl + a);
        acc1[n] = MFMA16(W2aH[k], bh, acc1[n]);
        acc2[n] = MFMA16(W2bH[k], bh, acc2[n]);
        acc1[n] = MFMA16(W2aH[k], bl, acc1[n]);
        acc2[n] = MFMA16(W2bH[k], bl, acc2[n]);
        acc1[n] = MFMA16(W2aL[k], bh, acc1[n]);
        acc2[n] = MFMA16(W2bL[k], bh, acc2[n]);
      }
      __builtin_amdgcn_s_setprio(0);
    }

    // ---- pre1/pre2 = relu(c - T) -> pre planes (b64 along d', slot-XOR swizzle) ----
    {
      const int c = wid*2 + (lg>>1);
      const int sub = (lg&1)*4;
      #pragma unroll
      for (int n=0;n<4;n++){
        const int row = n*16 + li;
        const int a = row*128 + ((c ^ li)<<3) + sub;
        u16x4 h4, l4, g4, m4;
        #pragma unroll
        for (int r=0;r<4;r++){
          float c1r = (r==0)?cv1.x:(r==1)?cv1.y:(r==2)?cv1.z:cv1.w;
          float c2r = (r==0)?cv2.x:(r==1)?cv2.y:(r==2)?cv2.z:cv2.w;
          float p1 = fmaxf(c1r - acc1[n][r], 0.f);
          float p2 = fmaxf(c2r - acc2[n][r], 0.f);
          u16 hh, ll;
          split_f32(p1, hh, ll); h4[r]=hh; l4[r]=ll;
          split_f32(p2, hh, ll); g4[r]=hh; m4[r]=ll;
        }
        *(u16x4*)&P1h[a] = h4; *(u16x4*)&P1l[a] = l4;
        *(u16x4*)&P2h[a] = g4; *(u16x4*)&P2l[a] = m4;
      }
    }
    // B2: pre planes visible; M buf[i&1] reads drained -> free for gather(i+2)
    asm volatile("s_waitcnt lgkmcnt(0)" ::: "memory");
    __builtin_amdgcn_s_barrier();
    __builtin_amdgcn_sched_barrier(0);

    if (i < 2) DO_GATHER(i+2, i&1);   // stays in flight across B3/B1 (counted vmcnt)

    // ---- fused GEMM2+GEMM3: h1 = Wc1 x pre1, h2 = Wc2 x pre2 ----
    f32x4 h1[4], h2[4];
    #pragma unroll
    for (int n=0;n<4;n++){ h1[n]=(f32x4)(0.f); h2[n]=(f32x4)(0.f); }
    #pragma unroll
    for (int k=0;k<4;k++){
      __builtin_amdgcn_s_setprio(1);
      #pragma unroll
      for (int n=0;n<4;n++){
        const int a = (n*16+li)*128 + (((k*4+lg) ^ li)<<3);
        bf16x8 p1h = *(const bf16x8*)(P1h + a);
        bf16x8 p1l = *(const bf16x8*)(P1l + a);
        bf16x8 p2h = *(const bf16x8*)(P2h + a);
        bf16x8 p2l = *(const bf16x8*)(P2l + a);
        h1[n] = MFMA16(VcaH[k], p1h, h1[n]);
        h2[n] = MFMA16(VcbH[k], p2h, h2[n]);
        h1[n] = MFMA16(VcaH[k], p1l, h1[n]);
        h2[n] = MFMA16(VcbH[k], p2l, h2[n]);
        h1[n] = MFMA16(VcaL[k], p1h, h1[n]);
        h2[n] = MFMA16(VcbL[k], p2h, h2[n]);
      }
      __builtin_amdgcn_s_setprio(0);
    }

    // ---- score partials: lane holds h[d'][s], d' = wid*16+lg*4+r, s = n*16+li ----
    #pragma unroll
    for (int n=0;n<4;n++){
      float p11=0.f, p22=0.f, p12=0.f;
      #pragma unroll
      for (int r=0;r<4;r++){
        float e1 = (r==0)?bb1.x:(r==1)?bb1.y:(r==2)?bb1.z:bb1.w;
        float e2 = (r==0)?bb2.x:(r==1)?bb2.y:(r==2)?bb2.z:bb2.w;
        float v1h = h1[n][r] + e1;
        float v2h = h2[n][r] + e2;
        p11 += v1h*v1h; p22 += v2h*v2h; p12 += v1h*v2h;
      }
      p11 += __shfl_xor(p11, 16, 64); p11 += __shfl_xor(p11, 32, 64);
      p22 += __shfl_xor(p22, 16, 64); p22 += __shfl_xor(p22, 32, 64);
      p12 += __shfl_xor(p12, 16, 64); p12 += __shfl_xor(p12, 32, 64);
      if (lane < 16){
        part[wid][n*16+li][0] = p11;
        part[wid][n*16+li][1] = p22;
        part[wid][n*16+li][2] = p12;
      }
    }
    // B3: partials visible (LDS only — gathers stay in flight)
    asm volatile("s_waitcnt lgkmcnt(0)" ::: "memory");
    __builtin_amdgcn_s_barrier();
    __builtin_amdgcn_sched_barrier(0);

    if (tid < 64){
      float S11=0.f, S22=0.f, S12=0.f;
      #pragma unroll
      for (int w=0; w<8; w++){
        S11 += part[w][tid][0]; S22 += part[w][tid][1]; S12 += part[w][tid][2];
      }
      float dot = S12 / sqrtf(S11 * S22);
      wss[(size_t)b*4096 + sbase + i*64 + tid] = expf((dot - 1.0f) * (1.0f/0.07f));
    }
  }
  #undef DO_GATHER
}

// ---------- split (+ optional copy): bank -> hi/lo planes ----------
__global__ __launch_bounds__(256) void split_copy_kernel(const float4* __restrict__ src,
    float4* __restrict__ dst, u16x4* __restrict__ mhp, u16x4* __restrict__ mlp,
    int n4, int docopy)
{
  int i = blockIdx.x*256 + threadIdx.x;
  const int stride = gridDim.x*256;
  for (; i < n4; i += stride){
    float4 f = src[i];
    if (docopy) dst[i] = f;
    u16x4 h, l; u16 hh, ll;
    split_f32(f.x, hh, ll); h[0]=hh; l[0]=ll;
    split_f32(f.y, hh, ll); h[1]=hh; l[1]=ll;
    split_f32(f.z, hh, ll); h[2]=hh; l[2]=ll;
    split_f32(f.w, hh, ll); h[3]=hh; l[3]=ll;
    mhp[i] = h; mlp[i] = l;
  }
}

__global__ __launch_bounds__(256) void copy_kernel(const float4* __restrict__ src,
                                                   float4* __restrict__ dst, int n4)
{
  int i = blockIdx.x*256 + threadIdx.x;
  const int stride = gridDim.x*256;
  for (; i < n4; i += stride) dst[i] = src[i];
}

__global__ __launch_bounds__(128) void update_kernel(const float* __restrict__ mem,
    const float* __restrict__ v2, const int* __restrict__ y, float* __restrict__ outmem)
{
  const int b = blockIdx.x;
  const int t = threadIdx.x;
  const int row = y[b];
  for (int b2=b+1; b2<64; ++b2) if (y[b2] == row) return;   // later duplicate wins
  float ab = 0.5f*mem[(size_t)row*128 + t] + 0.5f*v2[b*128 + t];
  __shared__ float red[2];
  float s = ab*ab;
  #pragma unroll
  for (int off=1; off<64; off<<=1) s += __shfl_xor(s, off, 64);
  if ((t & 63) == 0) red[t>>6] = s;
  __syncthreads();
  float tot = red[0] + red[1];
  outmem[(size_t)row*128 + t] = ab / sqrtf(tot);
}

// scores wss[b][s] -> out[s][b]
__global__ __launch_bounds__(256) void transpose_kernel(const float* __restrict__ wss,
                                                        float* __restrict__ out)
{
  __shared__ float tile[64][65];
  const int t = blockIdx.x;
  const int c = threadIdx.x & 63;
  const int r4 = threadIdx.x >> 6;
  #pragma unroll
  for (int i=0;i<16;i++){
    int bb = i*4 + r4;
    tile[bb][c] = wss[(size_t)bb*4096 + t*64 + c];
  }
  __syncthreads();
  #pragma unroll
  for (int i=0;i<16;i++){
    int s = i*4 + r4;
    out[(size_t)(t*64+s)*64 + c] = tile[c][s];
  }
}

extern "C" void kernel_launch(void* const* d_in, const int* in_sizes, int n_in,
                              void* d_out, int out_size, void* d_ws, size_t ws_size,
                              hipStream_t stream) {
  (void)in_sizes; (void)n_in; (void)out_size;
  const float* v1      = (const float*)d_in[0];
  const float* v2      = (const float*)d_in[1];
  const float* mem     = (const float*)d_in[2];
  const float* mt_w1   = (const float*)d_in[3];
  const float* mt_b1   = (const float*)d_in[4];
  const float* mt_w2   = (const float*)d_in[5];
  const float* mt_b2   = (const float*)d_in[6];
  const float* mt_wv   = (const float*)d_in[7];
  const float* mt_bv   = (const float*)d_in[8];
  const float* mts_w1  = (const float*)d_in[9];
  const float* mts_b1  = (const float*)d_in[10];
  const float* mts_w2  = (const float*)d_in[11];
  const float* mts_b2  = (const float*)d_in[12];
  const float* mts_wv  = (const float*)d_in[13];
  const float* mts_bv  = (const float*)d_in[14];
  const float* ht_w    = (const float*)d_in[15];
  const float* ht_b    = (const float*)d_in[16];
  const float* hts_w   = (const float*)d_in[17];
  const float* hts_b   = (const float*)d_in[18];
  const int*   y       = (const int*)d_in[19];
  const int*   idx     = (const int*)d_in[20];
  float* out = (float*)d_out;
  float* outmem = out + 262144;
  char* ws = (char*)d_ws;

  u16* w2a = (u16*)(ws + 0);
  u16* w2b = (u16*)(ws + 65536);
  u16* wc1 = (u16*)(ws + 131072);
  u16* wc2 = (u16*)(ws + 196608);
  float* c1   = (float*)(ws + 262144);
  float* c2   = (float*)(ws + 294912);
  float* bc1  = (float*)(ws + 327680);
  float* bc2  = (float*)(ws + 328192);
  float* wss  = (float*)(ws + 393216);   // 64*4096 f32 = 1MB

  const size_t PLANES_OFF = 2097152;
  const size_t PLANES_BYTES = (size_t)12800000 * 2 * 2;   // 51.2MB
  const bool bigws = ws_size >= PLANES_OFF + PLANES_BYTES;
  u16 *mh, *ml;
  if (bigws){ mh = (u16*)(ws + PLANES_OFF); }
  else      { mh = (u16*)outmem; }            // park planes in new_memory region
  ml = mh + 12800000;

  // 1. split bank to hi/lo planes (+ fused copy when planes don't alias outmem)
  split_copy_kernel<<<2048, 256, 0, stream>>>((const float4*)mem, (float4*)outmem,
                                              (u16x4*)mh, (u16x4*)ml, 3200000, bigws ? 1 : 0);
  // 2. weights/c/bc prep
  prep_kernel<<<512, 128, 0, stream>>>(v1, v2,
      mt_w1, mt_b1, mt_w2, mt_b2, mt_wv, mt_bv,
      mts_w1, mts_b1, mts_w2, mts_b2, mts_wv, mts_bv,
      ht_w, ht_b, hts_w, hts_b,
      w2a, w2b, wc1, wc2, c1, c2, bc1, bc2);
  // 3. main fused compute -> wss (1024 blocks x 512 thr = 1 block/CU, 4 tiles each)
  main_kernel<<<1024, 512, 0, stream>>>(mh, ml, idx,
      w2a, w2b, wc1, wc2, c1, c2, bc1, bc2, wss);
  // 4. new_memory
  if (!bigws)
    copy_kernel<<<2048, 256, 0, stream>>>((const float4*)mem, (float4*)outmem, 3200000);
  update_kernel<<<64, 128, 0, stream>>>(mem, v2, y, outmem);
  // 5. scores transpose into out
  transpose_kernel<<<64, 256, 0, stream>>>(wss, out);
}